// Round 3
// baseline (3271.560 us; speedup 1.0000x reference)
//
#include <hip/hip_runtime.h>
#include <cfloat>

#define NROWS 65536
#define DIM   256
#define KCB   4096

// ws layout (bytes):
//   [0,       16384)   : cref  float[4096]    (numpy-exact column sums of v^2)
//   [16384,   16392)   : double loss accumulator
//   [32768,   1081344) : int4  cand[65536]    (.x/.y/.z = top-3 cand, .w = chosen)
//   [1081344, 5275648) : VT    float[4096*256] (transposed codebook)

__device__ __forceinline__ bool better(float v1, int i1, float v2, int i2) {
    return (v1 < v2) || (v1 == v2 && i1 < i2);
}

// launder a float through a VGPR so hipcc cannot FMA-contract or reassociate it
__device__ __forceinline__ float opaque(float x) {
    asm volatile("" : "+v"(x));
    return x;
}

// ---------- kernel 1a: numpy-exact C_k = sequential sum_d fl(v[d][k]^2) --------
__global__ void vq_cref_kernel(const float* __restrict__ v,
                               float* __restrict__ cref,
                               double* __restrict__ acc) {
    int k = blockIdx.x * blockDim.x + threadIdx.x;
    if (blockIdx.x == 0 && threadIdx.x == 0) *acc = 0.0;
    float t = v[k];
    float c = opaque(t * t);
    for (int d = 1; d < DIM; ++d) {
        t = v[d * KCB + k];
        c = c + opaque(t * t);   // plain add of pre-rounded square, d ascending
    }
    cref[k] = c;
}

// ---------- kernel 1b: transpose V (D,K) -> VT (K,D) ---------------------------
__global__ void vq_transpose_kernel(const float* __restrict__ v,
                                    float* __restrict__ vt) {
    __shared__ float tile[32][33];
    int d0 = blockIdx.x * 32;
    int k0 = blockIdx.y * 32;
    int tx = threadIdx.x;
    int ty = threadIdx.y;
    #pragma unroll
    for (int i = 0; i < 32; i += 8)
        tile[ty + i][tx] = v[(d0 + ty + i) * KCB + k0 + tx];
    __syncthreads();
    #pragma unroll
    for (int i = 0; i < 32; i += 8)
        vt[(k0 + ty + i) * DIM + d0 + tx] = tile[tx][ty + i];
}

// ---------- kernel 2: tiled fp32 GEMM + running top-3 argmin -------------------
#define BM 64
#define BN 64
#define BK 16

__device__ __forceinline__ void insert3(float& v1, int& i1, float& v2, int& i2,
                                        float& v3, int& i3, float nv, int ni) {
    if (better(nv, ni, v1, i1)) {
        v3 = v2; i3 = i2; v2 = v1; i2 = i1; v1 = nv; i1 = ni;
    } else if (better(nv, ni, v2, i2)) {
        v3 = v2; i3 = i2; v2 = nv; i2 = ni;
    } else if (better(nv, ni, v3, i3)) {
        v3 = nv; i3 = ni;
    }
}

__global__ __launch_bounds__(256) void vq_argmin_kernel(
        const float* __restrict__ x, const float* __restrict__ v,
        const float* __restrict__ vnorm, int4* __restrict__ cand) {
    __shared__ float As[BK][BM];
    __shared__ float Bs[BK][BN];

    const int tid  = threadIdx.x;
    const int ty   = tid >> 4;
    const int tx   = tid & 15;
    const int row0 = blockIdx.x * BM;

    const int arow = tid >> 2;
    const int adq  = (tid & 3) * 4;
    const int bd   = tid >> 4;
    const int bk4  = (tid & 15) * 4;

    float b1v[4], b2v[4], b3v[4];
    int   b1i[4], b2i[4], b3i[4];
    #pragma unroll
    for (int i = 0; i < 4; ++i) {
        b1v[i] = FLT_MAX; b1i[i] = 0;
        b2v[i] = FLT_MAX; b2i[i] = 0;
        b3v[i] = FLT_MAX; b3i[i] = 0;
    }

    for (int kt = 0; kt < KCB; kt += BN) {
        float acc[4][4];
        #pragma unroll
        for (int i = 0; i < 4; ++i)
            #pragma unroll
            for (int j = 0; j < 4; ++j) acc[i][j] = 0.f;

        for (int dt = 0; dt < DIM; dt += BK) {
            float4 a = *(const float4*)&x[(row0 + arow) * DIM + dt + adq];
            float4 b = *(const float4*)&v[(dt + bd) * KCB + kt + bk4];
            As[adq + 0][arow] = a.x;
            As[adq + 1][arow] = a.y;
            As[adq + 2][arow] = a.z;
            As[adq + 3][arow] = a.w;
            *(float4*)&Bs[bd][bk4] = b;
            __syncthreads();
            #pragma unroll
            for (int kk = 0; kk < BK; ++kk) {
                float4 a4 = *(const float4*)&As[kk][ty * 4];
                float4 b4 = *(const float4*)&Bs[kk][tx * 4];
                acc[0][0] = fmaf(a4.x, b4.x, acc[0][0]);
                acc[0][1] = fmaf(a4.x, b4.y, acc[0][1]);
                acc[0][2] = fmaf(a4.x, b4.z, acc[0][2]);
                acc[0][3] = fmaf(a4.x, b4.w, acc[0][3]);
                acc[1][0] = fmaf(a4.y, b4.x, acc[1][0]);
                acc[1][1] = fmaf(a4.y, b4.y, acc[1][1]);
                acc[1][2] = fmaf(a4.y, b4.z, acc[1][2]);
                acc[1][3] = fmaf(a4.y, b4.w, acc[1][3]);
                acc[2][0] = fmaf(a4.z, b4.x, acc[2][0]);
                acc[2][1] = fmaf(a4.z, b4.y, acc[2][1]);
                acc[2][2] = fmaf(a4.z, b4.z, acc[2][2]);
                acc[2][3] = fmaf(a4.z, b4.w, acc[2][3]);
                acc[3][0] = fmaf(a4.w, b4.x, acc[3][0]);
                acc[3][1] = fmaf(a4.w, b4.y, acc[3][1]);
                acc[3][2] = fmaf(a4.w, b4.z, acc[3][2]);
                acc[3][3] = fmaf(a4.w, b4.w, acc[3][3]);
            }
            __syncthreads();
        }

        #pragma unroll
        for (int j = 0; j < 4; ++j) {
            int k = kt + tx * 4 + j;
            float vn = vnorm[k];
            #pragma unroll
            for (int i = 0; i < 4; ++i) {
                float s = fmaf(-2.f, acc[i][j], vn);
                if (s < b3v[i])   // strict <: equal-value-later-index loses anyway
                    insert3(b1v[i], b1i[i], b2v[i], b2i[i], b3v[i], b3i[i], s, k);
            }
        }
    }

    // butterfly-merge top-3 sets across the 16 tx lanes sharing each row
    #pragma unroll
    for (int off = 8; off > 0; off >>= 1) {
        #pragma unroll
        for (int i = 0; i < 4; ++i) {
            float ov1 = __shfl_xor(b1v[i], off);
            int   oi1 = __shfl_xor(b1i[i], off);
            float ov2 = __shfl_xor(b2v[i], off);
            int   oi2 = __shfl_xor(b2i[i], off);
            float ov3 = __shfl_xor(b3v[i], off);
            int   oi3 = __shfl_xor(b3i[i], off);
            insert3(b1v[i], b1i[i], b2v[i], b2i[i], b3v[i], b3i[i], ov1, oi1);
            insert3(b1v[i], b1i[i], b2v[i], b2i[i], b3v[i], b3i[i], ov2, oi2);
            insert3(b1v[i], b1i[i], b2v[i], b2i[i], b3v[i], b3i[i], ov3, oi3);
        }
    }
    if (tx == 0) {
        #pragma unroll
        for (int i = 0; i < 4; ++i)
            cand[row0 + ty * 4 + i] = make_int4(b1i[i], b2i[i], b3i[i], b1i[i]);
    }
}

// ---------- kernel 3: numpy-fp32 bit-exact re-score of top-3, select ----------
// Emulates: d_k = fl( fl(A - B_k) + C_k ), A = pairwise-sum(x^2) (numpy order),
// B_k = sequential-FMA sgemm dot of (2x, v_col_k), C_k = cref[k].
// np.argmin = lexicographic (value, index) min.
__global__ __launch_bounds__(256) void vq_emulate_kernel(
        const float* __restrict__ x, const float* __restrict__ vt,
        const float* __restrict__ cref, int4* __restrict__ cand,
        float* __restrict__ out_idx) {
    int row = blockIdx.x * blockDim.x + threadIdx.x;
    int4 c = cand[row];
    const float* xr = x + (size_t)row * DIM;
    const float* v0 = vt + (size_t)c.x * DIM;
    const float* v1 = vt + (size_t)c.y * DIM;
    const float* v2 = vt + (size_t)c.z * DIM;

    float b0 = 0.f, b1 = 0.f, b2 = 0.f;   // sgemm FMA accumulators (k ascending)
    float A_half[2];
    #pragma unroll
    for (int h = 0; h < 2; ++h) {
        float r[8];
        #pragma unroll
        for (int j = 0; j < 8; ++j) {
            int d = h * 128 + j;
            float xv = xr[d];
            r[j] = opaque(xv * xv);
            float t2 = 2.f * xv;
            b0 = fmaf(t2, v0[d], b0);
            b1 = fmaf(t2, v1[d], b1);
            b2 = fmaf(t2, v2[d], b2);
        }
        for (int i = 1; i < 16; ++i) {
            #pragma unroll
            for (int j = 0; j < 8; ++j) {
                int d = h * 128 + i * 8 + j;
                float xv = xr[d];
                r[j] = r[j] + opaque(xv * xv);
                float t2 = 2.f * xv;
                b0 = fmaf(t2, v0[d], b0);
                b1 = fmaf(t2, v1[d], b1);
                b2 = fmaf(t2, v2[d], b2);
            }
        }
        A_half[h] = ((r[0] + r[1]) + (r[2] + r[3])) + ((r[4] + r[5]) + (r[6] + r[7]));
    }
    float A = A_half[0] + A_half[1];

    float d0 = (A - b0) + cref[c.x];
    float d1 = (A - b1) + cref[c.y];
    float d2 = (A - b2) + cref[c.z];

    float bd = d0; int bk = c.x;
    if (better(d1, c.y, bd, bk)) { bd = d1; bk = c.y; }
    if (better(d2, c.z, bd, bk)) { bd = d2; bk = c.z; }

    ((int*)(cand + row))[3] = bk;
    out_idx[row] = (float)bk;
}

// ---------- kernel 4: gather chosen vector, write out_q, loss ------------------
__global__ __launch_bounds__(256) void vq_quant_kernel(
        const float* __restrict__ x, const float* __restrict__ vt,
        const int4* __restrict__ cand, float* __restrict__ out_q,
        double* __restrict__ acc) {
    const int tid    = threadIdx.x;
    const int rlocal = tid >> 6;
    const int lane   = tid & 63;
    const int row    = blockIdx.x * 4 + rlocal;
    const int k      = ((const int*)(cand + row))[3];

    float4 xv = *(const float4*)&x[(size_t)row * DIM + lane * 4];
    float4 q  = *(const float4*)&vt[(size_t)k * DIM + lane * 4];
    *(float4*)&out_q[(size_t)row * DIM + lane * 4] = q;

    float dx = xv.x - q.x, dy = xv.y - q.y, dz = xv.z - q.z, dw = xv.w - q.w;
    float sum = dx * dx + dy * dy + dz * dz + dw * dw;
    #pragma unroll
    for (int off = 32; off > 0; off >>= 1)
        sum += __shfl_xor(sum, off);

    __shared__ float bsum[4];
    if (lane == 0) bsum[rlocal] = sum;
    __syncthreads();
    if (tid == 0)
        atomicAdd(acc, (double)(bsum[0] + bsum[1] + bsum[2] + bsum[3]));
}

// ---------- kernel 5: finalize losses ------------------------------------------
__global__ void vq_finalize_kernel(const double* __restrict__ acc,
                                   float* __restrict__ out_loss) {
    double m = *acc / (double)((long long)NROWS * DIM);
    out_loss[0] = (float)m;   // dictionary_loss
    out_loss[1] = (float)m;   // commitment_loss (identical forward value)
}

extern "C" void kernel_launch(void* const* d_in, const int* in_sizes, int n_in,
                              void* d_out, int out_size, void* d_ws, size_t ws_size,
                              hipStream_t stream) {
    const float* x = (const float*)d_in[0];   // (64,1024,256)
    const float* v = (const float*)d_in[1];   // (256,4096)

    float* out      = (float*)d_out;
    float* out_q    = out;
    float* out_loss = out + (size_t)NROWS * DIM;
    float* out_idx  = out + (size_t)NROWS * DIM + 2;

    char*   ws   = (char*)d_ws;
    float*  cref = (float*)ws;
    double* acc  = (double*)(ws + 16384);
    int4*   cand = (int4*)(ws + 32768);
    float*  vt   = (float*)(ws + 1081344);

    vq_cref_kernel<<<KCB / 256, 256, 0, stream>>>(v, cref, acc);
    vq_transpose_kernel<<<dim3(DIM / 32, KCB / 32), dim3(32, 8), 0, stream>>>(v, vt);
    vq_argmin_kernel<<<NROWS / BM, 256, 0, stream>>>(x, v, cref, cand);
    vq_emulate_kernel<<<NROWS / 256, 256, 0, stream>>>(x, vt, cref, cand, out_idx);
    vq_quant_kernel<<<NROWS / 4, 256, 0, stream>>>(x, vt, cand, out_q, acc);
    vq_finalize_kernel<<<1, 1, 0, stream>>>(acc, out_loss);
}

// Round 4
// 1148.225 us; speedup vs baseline: 2.8492x; 2.8492x over previous
//
#include <hip/hip_runtime.h>
#include <cfloat>

#define NROWS 65536
#define DIM   256
#define KCB   4096

typedef __attribute__((ext_vector_type(8))) short bf16x8;
typedef __attribute__((ext_vector_type(4))) float f32x4;
typedef unsigned short ushort;
typedef unsigned int uint;

// ws layout (bytes):
//   [0,       16384)   : cref   float[4096]   (numpy-exact column sums of v^2)
//   [16384,   16392)   : double loss accumulator
//   [32768,   1081344) : int4   cand[65536]   (top-4 candidate indices)
//   [1081344, 1343488) : int    chosen[65536]
//   [1343488, 5537792) : vt     float[4096*256]  (transposed codebook, fp32)
//   [5537792, 7634944) : vth    ushort[4096*256] (transposed codebook, bf16)

__device__ __forceinline__ bool better(float v1, int i1, float v2, int i2) {
    return (v1 < v2) || (v1 == v2 && i1 < i2);
}

// launder through a VGPR so hipcc cannot FMA-contract or reassociate
__device__ __forceinline__ float opaque(float x) {
    asm volatile("" : "+v"(x));
    return x;
}

__device__ __forceinline__ ushort f2bf(float f) {   // RNE fp32 -> bf16
    uint u = __float_as_uint(f);
    return (ushort)((u + 0x7FFFu + ((u >> 16) & 1u)) >> 16);
}

// insert into ascending top-4 by value only (per-lane stream has ascending k,
// so strict < gives first-min tie-break)
__device__ __forceinline__ void insert4v(float v[4], int idx[4], float s, int k) {
    if (s < v[3]) {
        if (s < v[2]) {
            v[3] = v[2]; idx[3] = idx[2];
            if (s < v[1]) {
                v[2] = v[1]; idx[2] = idx[1];
                if (s < v[0]) {
                    v[1] = v[0]; idx[1] = idx[0]; v[0] = s; idx[0] = k;
                } else { v[1] = s; idx[1] = k; }
            } else { v[2] = s; idx[2] = k; }
        } else { v[3] = s; idx[3] = k; }
    }
}

// insert with (value, index) lexicographic order (for merges)
__device__ __forceinline__ void insert4b(float v[4], int idx[4], float s, int k) {
    if (better(s, k, v[3], idx[3])) {
        if (better(s, k, v[2], idx[2])) {
            v[3] = v[2]; idx[3] = idx[2];
            if (better(s, k, v[1], idx[1])) {
                v[2] = v[1]; idx[2] = idx[1];
                if (better(s, k, v[0], idx[0])) {
                    v[1] = v[0]; idx[1] = idx[0]; v[0] = s; idx[0] = k;
                } else { v[1] = s; idx[1] = k; }
            } else { v[2] = s; idx[2] = k; }
        } else { v[3] = s; idx[3] = k; }
    }
}

// ---------- kernel 1a: numpy-exact C_k = sequential sum_d fl(v[d][k]^2) --------
__global__ void vq_cref_kernel(const float* __restrict__ v,
                               float* __restrict__ cref,
                               double* __restrict__ acc) {
    int k = blockIdx.x * blockDim.x + threadIdx.x;
    if (blockIdx.x == 0 && threadIdx.x == 0) *acc = 0.0;
    float t = v[k];
    float c = opaque(t * t);
    for (int d = 1; d < DIM; ++d) {
        t = v[d * KCB + k];
        c = c + opaque(t * t);
    }
    cref[k] = c;
}

// ---------- kernel 1b: transpose V (D,K) -> vt fp32 + vth bf16 (both K,D) ------
__global__ void vq_transpose_kernel(const float* __restrict__ v,
                                    float* __restrict__ vt,
                                    ushort* __restrict__ vth) {
    __shared__ float tile[32][33];
    int d0 = blockIdx.x * 32;
    int k0 = blockIdx.y * 32;
    int tx = threadIdx.x;
    int ty = threadIdx.y;
    #pragma unroll
    for (int i = 0; i < 32; i += 8)
        tile[ty + i][tx] = v[(d0 + ty + i) * KCB + k0 + tx];
    __syncthreads();
    #pragma unroll
    for (int i = 0; i < 32; i += 8) {
        float val = tile[tx][ty + i];
        vt[(k0 + ty + i) * DIM + d0 + tx]  = val;
        vth[(k0 + ty + i) * DIM + d0 + tx] = f2bf(val);
    }
}

// ---------- kernel 2: bf16 MFMA GEMM + running top-4 argmin --------------------
// Block: 64 x-rows x all 4096 codes. Chunk: 256 codes (4 waves x 64-code
// stripe). A-operand = codebook (M=codes), B-operand = x rows (N), so each
// lane's C fragment holds 16 k-scores for ONE x-row per nj.
__global__ __launch_bounds__(256) void vq_mfma_argmin_kernel(
        const float* __restrict__ x, const ushort* __restrict__ vth,
        const float* __restrict__ cref_g, int4* __restrict__ cand) {
    __shared__ __align__(16) ushort Alds[256 * 40];   // codes x 32 bf16, pad->40
    __shared__ __align__(16) ushort Blds[64 * 40];    // x-rows x 32 bf16
    __shared__ float  crefs[KCB];
    __shared__ float2 mbuf[64 * 16];                  // [row][wave*4+slot]

    const int tid  = threadIdx.x;
    const int w    = tid >> 6;        // wave 0..3
    const int lane = tid & 63;
    const int l15  = lane & 15;
    const int quad = lane >> 4;
    const int row0 = blockIdx.x * 64;

    for (int i = tid; i < KCB; i += 256) crefs[i] = cref_g[i];

    float st_v[4][4];
    int   st_i[4][4];
    #pragma unroll
    for (int nj = 0; nj < 4; ++nj)
        #pragma unroll
        for (int s = 0; s < 4; ++s) { st_v[nj][s] = FLT_MAX; st_i[nj][s] = 0; }

    for (int kt = 0; kt < 16; ++kt) {
        f32x4 acc[4][4];
        #pragma unroll
        for (int mi = 0; mi < 4; ++mi)
            #pragma unroll
            for (int nj = 0; nj < 4; ++nj)
                acc[mi][nj] = (f32x4)0.f;

        for (int dt = 0; dt < 8; ++dt) {
            // stage A: 256 codes x 32 bf16 from vth (4 x 16B units/thread)
            #pragma unroll
            for (int r = 0; r < 4; ++r) {
                int u = tid + r * 256;
                int code = u >> 2, c8 = (u & 3) * 8;
                int4 d = *(const int4*)&vth[(size_t)(kt * 256 + code) * DIM + dt * 32 + c8];
                *(int4*)&Alds[code * 40 + c8] = d;
            }
            // stage B: 64 rows x 32 bf16, fp32->bf16 inline (1 unit/thread)
            {
                int row = tid >> 2, c8 = (tid & 3) * 8;
                const float* s = &x[(size_t)(row0 + row) * DIM + dt * 32 + c8];
                float4 f0 = *(const float4*)s;
                float4 f1 = *(const float4*)(s + 4);
                int4 p;
                p.x = (int)f2bf(f0.x) | ((int)f2bf(f0.y) << 16);
                p.y = (int)f2bf(f0.z) | ((int)f2bf(f0.w) << 16);
                p.z = (int)f2bf(f1.x) | ((int)f2bf(f1.y) << 16);
                p.w = (int)f2bf(f1.z) | ((int)f2bf(f1.w) << 16);
                *(int4*)&Blds[row * 40 + c8] = p;
            }
            __syncthreads();

            bf16x8 af[4], bfr[4];
            #pragma unroll
            for (int mi = 0; mi < 4; ++mi)
                af[mi] = *(const bf16x8*)&Alds[(w * 64 + mi * 16 + l15) * 40 + quad * 8];
            #pragma unroll
            for (int nj = 0; nj < 4; ++nj)
                bfr[nj] = *(const bf16x8*)&Blds[(nj * 16 + l15) * 40 + quad * 8];
            #pragma unroll
            for (int mi = 0; mi < 4; ++mi)
                #pragma unroll
                for (int nj = 0; nj < 4; ++nj)
                    acc[mi][nj] = __builtin_amdgcn_mfma_f32_16x16x32_bf16(
                        af[mi], bfr[nj], acc[mi][nj], 0, 0, 0);
            __syncthreads();
        }

        // fold: score = cref[k] - 2*dot; per-lane k ascending over (kt,mi,r)
        const int kb = kt * 256 + w * 64;
        #pragma unroll
        for (int mi = 0; mi < 4; ++mi) {
            #pragma unroll
            for (int r = 0; r < 4; ++r) {
                const int k = kb + mi * 16 + quad * 4 + r;
                const float cv = crefs[k];
                #pragma unroll
                for (int nj = 0; nj < 4; ++nj) {
                    float s = fmaf(-2.f, acc[mi][nj][r], cv);
                    insert4v(st_v[nj], st_i[nj], s, k);
                }
            }
        }
    }

    // butterfly-merge across the 4 quads holding the same x-row
    #pragma unroll
    for (int off = 16; off <= 32; off <<= 1) {
        #pragma unroll
        for (int nj = 0; nj < 4; ++nj) {
            float ov[4]; int oi[4];
            #pragma unroll
            for (int s = 0; s < 4; ++s) {
                ov[s] = __shfl_xor(st_v[nj][s], off);
                oi[s] = __shfl_xor(st_i[nj][s], off);
            }
            #pragma unroll
            for (int s = 0; s < 4; ++s)
                insert4b(st_v[nj], st_i[nj], ov[s], oi[s]);
        }
    }
    // cross-wave merge via LDS
    if (quad == 0) {
        #pragma unroll
        for (int nj = 0; nj < 4; ++nj) {
            int row_local = nj * 16 + l15;
            #pragma unroll
            for (int s = 0; s < 4; ++s)
                mbuf[row_local * 16 + w * 4 + s] =
                    make_float2(st_v[nj][s], __int_as_float(st_i[nj][s]));
        }
    }
    __syncthreads();
    if (tid < 64) {
        float bv[4] = {FLT_MAX, FLT_MAX, FLT_MAX, FLT_MAX};
        int   bi[4] = {0, 0, 0, 0};
        #pragma unroll
        for (int j = 0; j < 16; ++j) {
            float2 p = mbuf[tid * 16 + j];
            insert4b(bv, bi, p.x, __float_as_int(p.y));
        }
        cand[row0 + tid] = make_int4(bi[0], bi[1], bi[2], bi[3]);
    }
}

// ---------- kernel 3: numpy-fp32 bit-exact re-score of top-4, select ----------
__global__ __launch_bounds__(256) void vq_emulate_kernel(
        const float* __restrict__ x, const float* __restrict__ vt,
        const float* __restrict__ cref, const int4* __restrict__ cand,
        int* __restrict__ chosen, float* __restrict__ out_idx) {
    int row = blockIdx.x * blockDim.x + threadIdx.x;
    int4 c = cand[row];
    const float* xr = x + (size_t)row * DIM;
    const float* v0 = vt + (size_t)c.x * DIM;
    const float* v1 = vt + (size_t)c.y * DIM;
    const float* v2 = vt + (size_t)c.z * DIM;
    const float* v3 = vt + (size_t)c.w * DIM;

    float b0 = 0.f, b1 = 0.f, b2 = 0.f, b3 = 0.f;   // sgemm FMA accs, d ascending
    float A_half[2];
    #pragma unroll
    for (int h = 0; h < 2; ++h) {
        float r[8];
        #pragma unroll
        for (int j = 0; j < 8; ++j) {
            int d = h * 128 + j;
            float xv = xr[d];
            r[j] = opaque(xv * xv);
            float t2 = 2.f * xv;
            b0 = fmaf(t2, v0[d], b0);
            b1 = fmaf(t2, v1[d], b1);
            b2 = fmaf(t2, v2[d], b2);
            b3 = fmaf(t2, v3[d], b3);
        }
        for (int i = 1; i < 16; ++i) {
            #pragma unroll
            for (int j = 0; j < 8; ++j) {
                int d = h * 128 + i * 8 + j;
                float xv = xr[d];
                r[j] = r[j] + opaque(xv * xv);
                float t2 = 2.f * xv;
                b0 = fmaf(t2, v0[d], b0);
                b1 = fmaf(t2, v1[d], b1);
                b2 = fmaf(t2, v2[d], b2);
                b3 = fmaf(t2, v3[d], b3);
            }
        }
        A_half[h] = ((r[0] + r[1]) + (r[2] + r[3])) + ((r[4] + r[5]) + (r[6] + r[7]));
    }
    float A = A_half[0] + A_half[1];

    float d0 = (A - b0) + cref[c.x];
    float d1 = (A - b1) + cref[c.y];
    float d2 = (A - b2) + cref[c.z];
    float d3 = (A - b3) + cref[c.w];

    float bd = d0; int bk = c.x;
    if (better(d1, c.y, bd, bk)) { bd = d1; bk = c.y; }
    if (better(d2, c.z, bd, bk)) { bd = d2; bk = c.z; }
    if (better(d3, c.w, bd, bk)) { bd = d3; bk = c.w; }

    chosen[row]  = bk;
    out_idx[row] = (float)bk;
}

// ---------- kernel 4: gather chosen vector, write out_q, loss ------------------
__global__ __launch_bounds__(256) void vq_quant_kernel(
        const float* __restrict__ x, const float* __restrict__ vt,
        const int* __restrict__ chosen, float* __restrict__ out_q,
        double* __restrict__ acc) {
    const int tid    = threadIdx.x;
    const int rlocal = tid >> 6;
    const int lane   = tid & 63;
    const int row    = blockIdx.x * 4 + rlocal;
    const int k      = chosen[row];

    float4 xv = *(const float4*)&x[(size_t)row * DIM + lane * 4];
    float4 q  = *(const float4*)&vt[(size_t)k * DIM + lane * 4];
    *(float4*)&out_q[(size_t)row * DIM + lane * 4] = q;

    float dx = xv.x - q.x, dy = xv.y - q.y, dz = xv.z - q.z, dw = xv.w - q.w;
    float sum = dx * dx + dy * dy + dz * dz + dw * dw;
    #pragma unroll
    for (int off = 32; off > 0; off >>= 1)
        sum += __shfl_xor(sum, off);

    __shared__ float bsum[4];
    if (lane == 0) bsum[rlocal] = sum;
    __syncthreads();
    if (tid == 0)
        atomicAdd(acc, (double)(bsum[0] + bsum[1] + bsum[2] + bsum[3]));
}

// ---------- kernel 5: finalize losses ------------------------------------------
__global__ void vq_finalize_kernel(const double* __restrict__ acc,
                                   float* __restrict__ out_loss) {
    double m = *acc / (double)((long long)NROWS * DIM);
    out_loss[0] = (float)m;   // dictionary_loss
    out_loss[1] = (float)m;   // commitment_loss (identical forward value)
}

extern "C" void kernel_launch(void* const* d_in, const int* in_sizes, int n_in,
                              void* d_out, int out_size, void* d_ws, size_t ws_size,
                              hipStream_t stream) {
    const float* x = (const float*)d_in[0];   // (64,1024,256)
    const float* v = (const float*)d_in[1];   // (256,4096)

    float* out      = (float*)d_out;
    float* out_q    = out;
    float* out_loss = out + (size_t)NROWS * DIM;
    float* out_idx  = out + (size_t)NROWS * DIM + 2;

    char*   ws     = (char*)d_ws;
    float*  cref   = (float*)ws;
    double* acc    = (double*)(ws + 16384);
    int4*   cand   = (int4*)(ws + 32768);
    int*    chosen = (int*)(ws + 1081344);
    float*  vt     = (float*)(ws + 1343488);
    ushort* vth    = (ushort*)(ws + 5537792);

    vq_cref_kernel<<<KCB / 256, 256, 0, stream>>>(v, cref, acc);
    vq_transpose_kernel<<<dim3(DIM / 32, KCB / 32), dim3(32, 8), 0, stream>>>(v, vt, vth);
    vq_mfma_argmin_kernel<<<NROWS / 64, 256, 0, stream>>>(x, vth, cref, cand);
    vq_emulate_kernel<<<NROWS / 256, 256, 0, stream>>>(x, vt, cref, cand, chosen, out_idx);
    vq_quant_kernel<<<NROWS / 4, 256, 0, stream>>>(x, vt, chosen, out_q, acc);
    vq_finalize_kernel<<<1, 1, 0, stream>>>(acc, out_loss);
}

// Round 5
// 1073.181 us; speedup vs baseline: 3.0485x; 1.0699x over previous
//
#include <hip/hip_runtime.h>
#include <cfloat>

#define NROWS 65536
#define DIM   256
#define KCB   4096

typedef __attribute__((ext_vector_type(8))) short bf16x8;
typedef __attribute__((ext_vector_type(4))) float f32x4;
typedef unsigned short ushort;
typedef unsigned int uint;

// ws layout (bytes):
//   [0,       16384)   : cref   float[4096]   (numpy-exact column sums of v^2)
//   [16384,   16392)   : double loss accumulator
//   [32768,   1081344) : int4   cand[65536]   (top-4 candidate indices)
//   [1081344, 1343488) : int    chosen[65536]
//   [1343488, 5537792) : vt     float[4096*256]  (transposed codebook, fp32)
//   [5537792, 7634944) : vth    ushort[4096*256] (transposed codebook, bf16)

__device__ __forceinline__ bool better(float v1, int i1, float v2, int i2) {
    return (v1 < v2) || (v1 == v2 && i1 < i2);
}

// launder through a VGPR so hipcc cannot FMA-contract or reassociate
__device__ __forceinline__ float opaque(float x) {
    asm volatile("" : "+v"(x));
    return x;
}

__device__ __forceinline__ ushort f2bf(float f) {   // RNE fp32 -> bf16
    uint u = __float_as_uint(f);
    return (ushort)((u + 0x7FFFu + ((u >> 16) & 1u)) >> 16);
}

// insert into ascending top-4 by value only (per-lane stream has ascending k,
// so strict < gives first-min tie-break)
__device__ __forceinline__ void insert4v(float v[4], int idx[4], float s, int k) {
    if (s < v[3]) {
        if (s < v[2]) {
            v[3] = v[2]; idx[3] = idx[2];
            if (s < v[1]) {
                v[2] = v[1]; idx[2] = idx[1];
                if (s < v[0]) {
                    v[1] = v[0]; idx[1] = idx[0]; v[0] = s; idx[0] = k;
                } else { v[1] = s; idx[1] = k; }
            } else { v[2] = s; idx[2] = k; }
        } else { v[3] = s; idx[3] = k; }
    }
}

// insert with (value, index) lexicographic order (for merges)
__device__ __forceinline__ void insert4b(float v[4], int idx[4], float s, int k) {
    if (better(s, k, v[3], idx[3])) {
        if (better(s, k, v[2], idx[2])) {
            v[3] = v[2]; idx[3] = idx[2];
            if (better(s, k, v[1], idx[1])) {
                v[2] = v[1]; idx[2] = idx[1];
                if (better(s, k, v[0], idx[0])) {
                    v[1] = v[0]; idx[1] = idx[0]; v[0] = s; idx[0] = k;
                } else { v[1] = s; idx[1] = k; }
            } else { v[2] = s; idx[2] = k; }
        } else { v[3] = s; idx[3] = k; }
    }
}

// ---------- kernel 1a: numpy-exact C_k = sequential sum_d fl(v[d][k]^2) --------
__global__ void vq_cref_kernel(const float* __restrict__ v,
                               float* __restrict__ cref,
                               double* __restrict__ acc) {
    int k = blockIdx.x * blockDim.x + threadIdx.x;
    if (blockIdx.x == 0 && threadIdx.x == 0) *acc = 0.0;
    float t = v[k];
    float c = opaque(t * t);
    for (int d = 1; d < DIM; ++d) {
        t = v[d * KCB + k];
        c = c + opaque(t * t);
    }
    cref[k] = c;
}

// ---------- kernel 1b: transpose V (D,K) -> vt fp32 + vth bf16 (both K,D) ------
__global__ void vq_transpose_kernel(const float* __restrict__ v,
                                    float* __restrict__ vt,
                                    ushort* __restrict__ vth) {
    __shared__ float tile[32][33];
    int d0 = blockIdx.x * 32;
    int k0 = blockIdx.y * 32;
    int tx = threadIdx.x;
    int ty = threadIdx.y;
    #pragma unroll
    for (int i = 0; i < 32; i += 8)
        tile[ty + i][tx] = v[(d0 + ty + i) * KCB + k0 + tx];
    __syncthreads();
    #pragma unroll
    for (int i = 0; i < 32; i += 8) {
        float val = tile[tx][ty + i];
        vt[(k0 + ty + i) * DIM + d0 + tx]  = val;
        vth[(k0 + ty + i) * DIM + d0 + tx] = f2bf(val);
    }
}

// ---------- kernel 2: bf16 MFMA + top-4 argmin, barrier-free K-loop ------------
// Block: 64 x-rows x all 4096 codes. x-tile converted to bf16 k-major LDS once;
// A fragments (codebook) loaded directly from L2-resident vth. No barriers in
// the main loop. Fold uses a min-tree fast path.
__global__ __launch_bounds__(256, 3) void vq_mfma_argmin_kernel(
        const float* __restrict__ x, const ushort* __restrict__ vth,
        const float* __restrict__ cref, int4* __restrict__ cand) {
    // Bk[u][r][8]: unit u = 8 bf16 of dims [u*8, u*8+8), r = x-row 0..63
    __shared__ __align__(16) ushort Bk[32 * 64 * 8];      // 32 KB
    __shared__ float2 mbuf[64 * 16];                      // 8 KB

    const int tid  = threadIdx.x;
    const int w    = tid >> 6;        // wave 0..3
    const int lane = tid & 63;
    const int l15  = lane & 15;
    const int quad = lane >> 4;
    const int row0 = blockIdx.x * 64;

    // ---- stage x-tile once: 64 rows x 256 dims -> bf16, k-major ----
    {
        const int r_ = tid >> 2;          // row 0..63
        const int q_ = tid & 3;           // quarter of the dims
        const float* xs = &x[(size_t)(row0 + r_) * DIM + q_ * 64];
        #pragma unroll
        for (int i = 0; i < 8; ++i) {
            float4 f0 = *(const float4*)(xs + i * 8);
            float4 f1 = *(const float4*)(xs + i * 8 + 4);
            int4 p;
            p.x = (int)f2bf(f0.x) | ((int)f2bf(f0.y) << 16);
            p.y = (int)f2bf(f0.z) | ((int)f2bf(f0.w) << 16);
            p.z = (int)f2bf(f1.x) | ((int)f2bf(f1.y) << 16);
            p.w = (int)f2bf(f1.z) | ((int)f2bf(f1.w) << 16);
            int u = q_ * 8 + i;
            *(int4*)&Bk[(u * 64 + r_) * 8] = p;
        }
    }
    __syncthreads();

    float st_v[4][4];
    int   st_i[4][4];
    #pragma unroll
    for (int nj = 0; nj < 4; ++nj)
        #pragma unroll
        for (int s = 0; s < 4; ++s) { st_v[nj][s] = FLT_MAX; st_i[nj][s] = 0; }

    // per-lane A row base: code = kt*256 + w*64 + mi*16 + l15, dims quad*8 within dt*32
    const ushort* abase = vth + (size_t)(w * 64 + l15) * DIM + quad * 8;

    for (int kt = 0; kt < 16; ++kt) {
        f32x4 acc[4][4];
        #pragma unroll
        for (int mi = 0; mi < 4; ++mi)
            #pragma unroll
            for (int nj = 0; nj < 4; ++nj)
                acc[mi][nj] = (f32x4)0.f;

        const ushort* akt = abase + (size_t)kt * 256 * DIM;

        #pragma unroll 2
        for (int dt = 0; dt < 8; ++dt) {
            bf16x8 af[4], bfr[4];
            #pragma unroll
            for (int mi = 0; mi < 4; ++mi)
                af[mi] = *(const bf16x8*)(akt + mi * 16 * DIM + dt * 32);
            #pragma unroll
            for (int nj = 0; nj < 4; ++nj)
                bfr[nj] = *(const bf16x8*)&Bk[((dt * 4 + quad) * 64 + nj * 16 + l15) * 8];
            #pragma unroll
            for (int mi = 0; mi < 4; ++mi)
                #pragma unroll
                for (int nj = 0; nj < 4; ++nj)
                    acc[mi][nj] = __builtin_amdgcn_mfma_f32_16x16x32_bf16(
                        af[mi], bfr[nj], acc[mi][nj], 0, 0, 0);
        }

        // ---- fold: score = cref[k] - 2*dot; min-tree fast path ----
        const int kb = kt * 256 + w * 64;
        float4 cv[4];
        #pragma unroll
        for (int mi = 0; mi < 4; ++mi)
            cv[mi] = *(const float4*)&cref[kb + mi * 16 + quad * 4];

        #pragma unroll
        for (int nj = 0; nj < 4; ++nj) {
            float sv[16];
            float m = FLT_MAX;
            #pragma unroll
            for (int mi = 0; mi < 4; ++mi) {
                #pragma unroll
                for (int r = 0; r < 4; ++r) {
                    float s = fmaf(-2.f, acc[mi][nj][r], (&cv[mi].x)[r]);
                    sv[mi * 4 + r] = s;
                    m = fminf(m, s);
                }
            }
            if (m < st_v[nj][3]) {          // rare slow path (exec-masked)
                #pragma unroll
                for (int mi = 0; mi < 4; ++mi)
                    #pragma unroll
                    for (int r = 0; r < 4; ++r)
                        insert4v(st_v[nj], st_i[nj], sv[mi * 4 + r],
                                 kb + mi * 16 + quad * 4 + r);
            }
        }
    }

    // butterfly-merge across the 4 quads holding the same x-row
    #pragma unroll
    for (int off = 16; off <= 32; off <<= 1) {
        #pragma unroll
        for (int nj = 0; nj < 4; ++nj) {
            float ov[4]; int oi[4];
            #pragma unroll
            for (int s = 0; s < 4; ++s) {
                ov[s] = __shfl_xor(st_v[nj][s], off);
                oi[s] = __shfl_xor(st_i[nj][s], off);
            }
            #pragma unroll
            for (int s = 0; s < 4; ++s)
                insert4b(st_v[nj], st_i[nj], ov[s], oi[s]);
        }
    }
    // cross-wave merge via LDS
    if (quad == 0) {
        #pragma unroll
        for (int nj = 0; nj < 4; ++nj) {
            int row_local = nj * 16 + l15;
            #pragma unroll
            for (int s = 0; s < 4; ++s)
                mbuf[row_local * 16 + w * 4 + s] =
                    make_float2(st_v[nj][s], __int_as_float(st_i[nj][s]));
        }
    }
    __syncthreads();
    if (tid < 64) {
        float bv[4] = {FLT_MAX, FLT_MAX, FLT_MAX, FLT_MAX};
        int   bi[4] = {0, 0, 0, 0};
        #pragma unroll
        for (int j = 0; j < 16; ++j) {
            float2 p = mbuf[tid * 16 + j];
            insert4b(bv, bi, p.x, __float_as_int(p.y));
        }
        cand[row0 + tid] = make_int4(bi[0], bi[1], bi[2], bi[3]);
    }
}

// ---------- kernel 3: numpy-fp32 bit-exact re-score of top-4, select ----------
// One thread per (row, candidate). A (pairwise x^2 sum) computed redundantly
// per lane in the exact numpy order; B chain per candidate identical to the
// r3/r4-validated sequence. Lex-min select via 2 shuffles.
__global__ __launch_bounds__(256) void vq_emulate_kernel(
        const float* __restrict__ x, const float* __restrict__ vt,
        const float* __restrict__ cref, const int4* __restrict__ cand,
        int* __restrict__ chosen, float* __restrict__ out_idx) {
    int gid = blockIdx.x * blockDim.x + threadIdx.x;
    int row = gid >> 2;
    int c   = ((const int*)cand)[gid];   // candidate (gid&3) of this row

    const float* xr = x + (size_t)row * DIM;
    const float* vr = vt + (size_t)c * DIM;

    float b = 0.f;                       // sgemm FMA accumulator, d ascending
    float A_half[2];
    #pragma unroll
    for (int h = 0; h < 2; ++h) {
        float r[8];
        #pragma unroll
        for (int j = 0; j < 8; ++j) {
            int d = h * 128 + j;
            float xv = xr[d];
            r[j] = opaque(xv * xv);
            b = fmaf(2.f * xv, vr[d], b);
        }
        for (int i = 1; i < 16; ++i) {
            #pragma unroll
            for (int j = 0; j < 8; ++j) {
                int d = h * 128 + i * 8 + j;
                float xv = xr[d];
                r[j] = r[j] + opaque(xv * xv);
                b = fmaf(2.f * xv, vr[d], b);
            }
        }
        A_half[h] = ((r[0] + r[1]) + (r[2] + r[3])) + ((r[4] + r[5]) + (r[6] + r[7]));
    }
    float A = A_half[0] + A_half[1];

    float bd = (A - b) + cref[c];
    int   bk = c;
    #pragma unroll
    for (int off = 1; off <= 2; off <<= 1) {
        float ov = __shfl_xor(bd, off);
        int   oi = __shfl_xor(bk, off);
        if (better(ov, oi, bd, bk)) { bd = ov; bk = oi; }
    }
    if ((gid & 3) == 0) {
        chosen[row]  = bk;
        out_idx[row] = (float)bk;
    }
}

// ---------- kernel 4: gather chosen vector, write out_q, loss ------------------
__global__ __launch_bounds__(256) void vq_quant_kernel(
        const float* __restrict__ x, const float* __restrict__ vt,
        const int* __restrict__ chosen, float* __restrict__ out_q,
        double* __restrict__ acc) {
    const int tid    = threadIdx.x;
    const int rlocal = tid >> 6;
    const int lane   = tid & 63;
    const int row    = blockIdx.x * 4 + rlocal;
    const int k      = chosen[row];

    float4 xv = *(const float4*)&x[(size_t)row * DIM + lane * 4];
    float4 q  = *(const float4*)&vt[(size_t)k * DIM + lane * 4];
    *(float4*)&out_q[(size_t)row * DIM + lane * 4] = q;

    float dx = xv.x - q.x, dy = xv.y - q.y, dz = xv.z - q.z, dw = xv.w - q.w;
    float sum = dx * dx + dy * dy + dz * dz + dw * dw;
    #pragma unroll
    for (int off = 32; off > 0; off >>= 1)
        sum += __shfl_xor(sum, off);

    __shared__ float bsum[4];
    if (lane == 0) bsum[rlocal] = sum;
    __syncthreads();
    if (tid == 0)
        atomicAdd(acc, (double)(bsum[0] + bsum[1] + bsum[2] + bsum[3]));
}

// ---------- kernel 5: finalize losses ------------------------------------------
__global__ void vq_finalize_kernel(const double* __restrict__ acc,
                                   float* __restrict__ out_loss) {
    double m = *acc / (double)((long long)NROWS * DIM);
    out_loss[0] = (float)m;   // dictionary_loss
    out_loss[1] = (float)m;   // commitment_loss (identical forward value)
}

extern "C" void kernel_launch(void* const* d_in, const int* in_sizes, int n_in,
                              void* d_out, int out_size, void* d_ws, size_t ws_size,
                              hipStream_t stream) {
    const float* x = (const float*)d_in[0];   // (64,1024,256)
    const float* v = (const float*)d_in[1];   // (256,4096)

    float* out      = (float*)d_out;
    float* out_q    = out;
    float* out_loss = out + (size_t)NROWS * DIM;
    float* out_idx  = out + (size_t)NROWS * DIM + 2;

    char*   ws     = (char*)d_ws;
    float*  cref   = (float*)ws;
    double* acc    = (double*)(ws + 16384);
    int4*   cand   = (int4*)(ws + 32768);
    int*    chosen = (int*)(ws + 1081344);
    float*  vt     = (float*)(ws + 1343488);
    ushort* vth    = (ushort*)(ws + 5537792);

    vq_cref_kernel<<<KCB / 256, 256, 0, stream>>>(v, cref, acc);
    vq_transpose_kernel<<<dim3(DIM / 32, KCB / 32), dim3(32, 8), 0, stream>>>(v, vt, vth);
    vq_mfma_argmin_kernel<<<NROWS / 64, 256, 0, stream>>>(x, vth, cref, cand);
    vq_emulate_kernel<<<NROWS * 4 / 256, 256, 0, stream>>>(x, vt, cref, cand, chosen, out_idx);
    vq_quant_kernel<<<NROWS / 4, 256, 0, stream>>>(x, vt, chosen, out_q, acc);
    vq_finalize_kernel<<<1, 1, 0, stream>>>(acc, out_loss);
}

// Round 6
// 510.371 us; speedup vs baseline: 6.4102x; 2.1027x over previous
//
#include <hip/hip_runtime.h>
#include <cfloat>

#define NROWS 65536
#define DIM   256
#define KCB   4096

typedef __attribute__((ext_vector_type(8))) short bf16x8;
typedef __attribute__((ext_vector_type(4))) float f32x4;
typedef unsigned short ushort;
typedef unsigned int uint;

// ws layout (bytes):
//   [0,       16384)   : cref    float[4096]    (numpy-exact column sums of v^2)
//   [32768,   1081344) : int4    cand[65536]    (.x..z top cands, .w = chosen)
//   [1081344, 1146880) : float   partial[16384] (per-quant-block loss partials)
//   [1343488, 5537792) : vt      float[4096*256]  (transposed codebook, fp32)
//   [5537792, 7634944) : vth     ushort[4096*256] (transposed codebook, bf16)

__device__ __forceinline__ bool better(float v1, int i1, float v2, int i2) {
    return (v1 < v2) || (v1 == v2 && i1 < i2);
}

// launder through a VGPR so hipcc cannot FMA-contract or reassociate
__device__ __forceinline__ float opaque(float x) {
    asm volatile("" : "+v"(x));
    return x;
}

__device__ __forceinline__ ushort f2bf(float f) {   // RNE fp32 -> bf16
    uint u = __float_as_uint(f);
    return (ushort)((u + 0x7FFFu + ((u >> 16) & 1u)) >> 16);
}

// branchless top-2 insert, value-only compare (per-lane stream has ascending k)
__device__ __forceinline__ void insert2v(float& v0, int& i0, float& v1, int& i1,
                                         float s, int k) {
    bool lt1 = s < v1;
    bool lt0 = s < v0;
    v1 = lt0 ? v0 : (lt1 ? s : v1);
    i1 = lt0 ? i0 : (lt1 ? k : i1);
    v0 = lt0 ? s : v0;
    i0 = lt0 ? k : i0;
}

// lexicographic top-4 insert (for merges)
__device__ __forceinline__ void insert4b(float v[4], int idx[4], float s, int k) {
    if (better(s, k, v[3], idx[3])) {
        if (better(s, k, v[2], idx[2])) {
            v[3] = v[2]; idx[3] = idx[2];
            if (better(s, k, v[1], idx[1])) {
                v[2] = v[1]; idx[2] = idx[1];
                if (better(s, k, v[0], idx[0])) {
                    v[1] = v[0]; idx[1] = idx[0]; v[0] = s; idx[0] = k;
                } else { v[1] = s; idx[1] = k; }
            } else { v[2] = s; idx[2] = k; }
        } else { v[3] = s; idx[3] = k; }
    }
}

// ---------- kernel 1a: numpy-exact C_k = sequential sum_d fl(v[d][k]^2) --------
__global__ void vq_cref_kernel(const float* __restrict__ v,
                               float* __restrict__ cref) {
    int k = blockIdx.x * blockDim.x + threadIdx.x;
    float t = v[k];
    float c = opaque(t * t);
    for (int d = 1; d < DIM; ++d) {
        t = v[d * KCB + k];
        c = c + opaque(t * t);
    }
    cref[k] = c;
}

// ---------- kernel 1b: transpose V (D,K) -> vt fp32 + vth bf16 (both K,D) ------
__global__ void vq_transpose_kernel(const float* __restrict__ v,
                                    float* __restrict__ vt,
                                    ushort* __restrict__ vth) {
    __shared__ float tile[32][33];
    int d0 = blockIdx.x * 32;
    int k0 = blockIdx.y * 32;
    int tx = threadIdx.x;
    int ty = threadIdx.y;
    #pragma unroll
    for (int i = 0; i < 32; i += 8)
        tile[ty + i][tx] = v[(d0 + ty + i) * KCB + k0 + tx];
    __syncthreads();
    #pragma unroll
    for (int i = 0; i < 32; i += 8) {
        float val = tile[tx][ty + i];
        vt[(k0 + ty + i) * DIM + d0 + tx]  = val;
        vth[(k0 + ty + i) * DIM + d0 + tx] = f2bf(val);
    }
}

// ---------- kernel 2: bf16 MFMA + top-2/lane argmin, barrier-free K-loop -------
__global__ __launch_bounds__(256, 4) void vq_mfma_argmin_kernel(
        const float* __restrict__ x, const ushort* __restrict__ vth,
        const float* __restrict__ cref, int4* __restrict__ cand) {
    // Bk[u][r][8]: unit u = 8 bf16 of dims [u*8,u*8+8), r = x-row; reused as mbuf
    __shared__ __align__(16) ushort Bk[32 * 64 * 8];      // 32 KB

    const int tid  = threadIdx.x;
    const int w    = tid >> 6;        // wave 0..3
    const int lane = tid & 63;
    const int l15  = lane & 15;
    const int quad = lane >> 4;
    const int row0 = blockIdx.x * 64;

    // ---- stage x-tile once: 64 rows x 256 dims -> bf16, k-major ----
    {
        const int r_ = tid >> 2;
        const int q_ = tid & 3;
        const float* xs = &x[(size_t)(row0 + r_) * DIM + q_ * 64];
        #pragma unroll
        for (int i = 0; i < 8; ++i) {
            float4 f0 = *(const float4*)(xs + i * 8);
            float4 f1 = *(const float4*)(xs + i * 8 + 4);
            int4 p;
            p.x = (int)f2bf(f0.x) | ((int)f2bf(f0.y) << 16);
            p.y = (int)f2bf(f0.z) | ((int)f2bf(f0.w) << 16);
            p.z = (int)f2bf(f1.x) | ((int)f2bf(f1.y) << 16);
            p.w = (int)f2bf(f1.z) | ((int)f2bf(f1.w) << 16);
            int u = q_ * 8 + i;
            *(int4*)&Bk[(u * 64 + r_) * 8] = p;
        }
    }
    __syncthreads();

    float s0[4], s1[4];
    int   j0[4], j1[4];
    #pragma unroll
    for (int nj = 0; nj < 4; ++nj) {
        s0[nj] = FLT_MAX; j0[nj] = 0;
        s1[nj] = FLT_MAX; j1[nj] = 0;
    }

    const ushort* abase = vth + (size_t)(w * 64 + l15) * DIM + quad * 8;

    for (int kt = 0; kt < 16; ++kt) {
        f32x4 acc[4][4];
        #pragma unroll
        for (int mi = 0; mi < 4; ++mi)
            #pragma unroll
            for (int nj = 0; nj < 4; ++nj)
                acc[mi][nj] = (f32x4)0.f;

        const ushort* akt = abase + (size_t)kt * 256 * DIM;

        #pragma unroll 2
        for (int dt = 0; dt < 8; ++dt) {
            bf16x8 af[4], bfr[4];
            #pragma unroll
            for (int mi = 0; mi < 4; ++mi)
                af[mi] = *(const bf16x8*)(akt + mi * 16 * DIM + dt * 32);
            #pragma unroll
            for (int nj = 0; nj < 4; ++nj)
                bfr[nj] = *(const bf16x8*)&Bk[((dt * 4 + quad) * 64 + nj * 16 + l15) * 8];
            #pragma unroll
            for (int mi = 0; mi < 4; ++mi)
                #pragma unroll
                for (int nj = 0; nj < 4; ++nj)
                    acc[mi][nj] = __builtin_amdgcn_mfma_f32_16x16x32_bf16(
                        af[mi], bfr[nj], acc[mi][nj], 0, 0, 0);
        }

        // ---- fold: score = cref[k] - 2*dot; min-tree gate + cheap top-2 ----
        const int kb = kt * 256 + w * 64;
        float4 cv[4];
        #pragma unroll
        for (int mi = 0; mi < 4; ++mi)
            cv[mi] = *(const float4*)&cref[kb + mi * 16 + quad * 4];

        #pragma unroll
        for (int nj = 0; nj < 4; ++nj) {
            float sv[16];
            float m = FLT_MAX;
            #pragma unroll
            for (int mi = 0; mi < 4; ++mi) {
                #pragma unroll
                for (int r = 0; r < 4; ++r) {
                    float s = fmaf(-2.f, acc[mi][nj][r], (&cv[mi].x)[r]);
                    sv[mi * 4 + r] = s;
                    m = fminf(m, s);
                }
            }
            if (m < s1[nj]) {          // exec-masked slow path, 8 VALU/insert
                #pragma unroll
                for (int mi = 0; mi < 4; ++mi)
                    #pragma unroll
                    for (int r = 0; r < 4; ++r)
                        insert2v(s0[nj], j0[nj], s1[nj], j1[nj],
                                 sv[mi * 4 + r], kb + mi * 16 + quad * 4 + r);
            }
        }
    }

    // expand to top-4 and butterfly-merge across the 4 quads of each row
    float mv[4][4];
    int   mi_[4][4];
    #pragma unroll
    for (int nj = 0; nj < 4; ++nj) {
        mv[nj][0] = s0[nj]; mi_[nj][0] = j0[nj];
        mv[nj][1] = s1[nj]; mi_[nj][1] = j1[nj];
        mv[nj][2] = FLT_MAX; mi_[nj][2] = 0;
        mv[nj][3] = FLT_MAX; mi_[nj][3] = 0;
    }
    #pragma unroll
    for (int off = 16; off <= 32; off <<= 1) {
        #pragma unroll
        for (int nj = 0; nj < 4; ++nj) {
            float ov[4]; int oi[4];
            #pragma unroll
            for (int s = 0; s < 4; ++s) {
                ov[s] = __shfl_xor(mv[nj][s], off);
                oi[s] = __shfl_xor(mi_[nj][s], off);
            }
            #pragma unroll
            for (int s = 0; s < 4; ++s)
                insert4b(mv[nj], mi_[nj], ov[s], oi[s]);
        }
    }

    __syncthreads();                    // all waves done reading Bk
    float2* mbuf = (float2*)Bk;         // overlay merge buffer on Bk
    if (quad == 0) {
        #pragma unroll
        for (int nj = 0; nj < 4; ++nj) {
            int row_local = nj * 16 + l15;
            #pragma unroll
            for (int s = 0; s < 4; ++s)
                mbuf[row_local * 16 + w * 4 + s] =
                    make_float2(mv[nj][s], __int_as_float(mi_[nj][s]));
        }
    }
    __syncthreads();
    if (tid < 64) {
        float bv[4] = {FLT_MAX, FLT_MAX, FLT_MAX, FLT_MAX};
        int   bi[4] = {0, 0, 0, 0};
        #pragma unroll
        for (int j = 0; j < 16; ++j) {
            float2 p = mbuf[tid * 16 + j];
            insert4b(bv, bi, p.x, __float_as_int(p.y));
        }
        cand[row0 + tid] = make_int4(bi[0], bi[1], bi[2], bi[3]);
    }
}

// ---------- kernel 3: numpy-fp32 bit-exact re-score of top-4, select ----------
// One thread per (row, candidate); float4 loads, scalar numpy-order arithmetic.
// Winner written into cand[row].w (wave-synchronous, after all lanes loaded).
__global__ __launch_bounds__(256) void vq_emulate_kernel(
        const float* __restrict__ x, const float* __restrict__ vt,
        const float* __restrict__ cref, int4* __restrict__ cand,
        float* __restrict__ out_idx) {
    int gid = blockIdx.x * blockDim.x + threadIdx.x;
    int row = gid >> 2;
    int c   = ((const int*)cand)[gid];

    const float4* xr = (const float4*)(x + (size_t)row * DIM);
    const float4* vr = (const float4*)(vt + (size_t)c * DIM);

    float b = 0.f;                      // sgemm FMA accumulator, d ascending
    float A_half[2];
    #pragma unroll
    for (int h = 0; h < 2; ++h) {
        float r[8];
        for (int i = 0; i < 16; ++i) {
            float4 xa = xr[h * 32 + i * 2];
            float4 xb = xr[h * 32 + i * 2 + 1];
            float4 va = vr[h * 32 + i * 2];
            float4 vb = vr[h * 32 + i * 2 + 1];
            float xs[8] = {xa.x, xa.y, xa.z, xa.w, xb.x, xb.y, xb.z, xb.w};
            float vs[8] = {va.x, va.y, va.z, va.w, vb.x, vb.y, vb.z, vb.w};
            if (i == 0) {
                #pragma unroll
                for (int j = 0; j < 8; ++j) {
                    r[j] = opaque(xs[j] * xs[j]);
                    b = fmaf(2.f * xs[j], vs[j], b);
                }
            } else {
                #pragma unroll
                for (int j = 0; j < 8; ++j) {
                    r[j] = r[j] + opaque(xs[j] * xs[j]);
                    b = fmaf(2.f * xs[j], vs[j], b);
                }
            }
        }
        A_half[h] = ((r[0] + r[1]) + (r[2] + r[3])) + ((r[4] + r[5]) + (r[6] + r[7]));
    }
    float A = A_half[0] + A_half[1];

    float bd = (A - b) + cref[c];
    int   bk = c;
    #pragma unroll
    for (int off = 1; off <= 2; off <<= 1) {
        float ov = __shfl_xor(bd, off);
        int   oi = __shfl_xor(bk, off);
        if (better(ov, oi, bd, bk)) { bd = ov; bk = oi; }
    }
    if ((gid & 3) == 0) {
        ((int*)(cand + row))[3] = bk;   // safe: all lane loads precede this store
        out_idx[row] = (float)bk;
    }
}

// ---------- kernel 4: gather chosen vector, write out_q, loss partial ----------
__global__ __launch_bounds__(256) void vq_quant_kernel(
        const float* __restrict__ x, const float* __restrict__ vt,
        const int4* __restrict__ cand, float* __restrict__ out_q,
        float* __restrict__ partial) {
    const int tid    = threadIdx.x;
    const int rlocal = tid >> 6;
    const int lane   = tid & 63;
    const int row    = blockIdx.x * 4 + rlocal;
    const int k      = ((const int*)(cand + row))[3];

    float4 xv = *(const float4*)&x[(size_t)row * DIM + lane * 4];
    float4 q  = *(const float4*)&vt[(size_t)k * DIM + lane * 4];
    *(float4*)&out_q[(size_t)row * DIM + lane * 4] = q;

    float dx = xv.x - q.x, dy = xv.y - q.y, dz = xv.z - q.z, dw = xv.w - q.w;
    float sum = dx * dx + dy * dy + dz * dz + dw * dw;
    #pragma unroll
    for (int off = 32; off > 0; off >>= 1)
        sum += __shfl_xor(sum, off);

    __shared__ float bsum[4];
    if (lane == 0) bsum[rlocal] = sum;
    __syncthreads();
    if (tid == 0)
        partial[blockIdx.x] = bsum[0] + bsum[1] + bsum[2] + bsum[3];
}

// ---------- kernel 5: reduce partials, finalize losses -------------------------
__global__ void vq_finalize_kernel(const float* __restrict__ partial,
                                   float* __restrict__ out_loss) {
    __shared__ double sd[256];
    double s = 0.0;
    for (int i = threadIdx.x; i < NROWS / 4; i += 256)
        s += (double)partial[i];
    sd[threadIdx.x] = s;
    __syncthreads();
    for (int off = 128; off > 0; off >>= 1) {
        if (threadIdx.x < off) sd[threadIdx.x] += sd[threadIdx.x + off];
        __syncthreads();
    }
    if (threadIdx.x == 0) {
        double m = sd[0] / (double)((long long)NROWS * DIM);
        out_loss[0] = (float)m;   // dictionary_loss
        out_loss[1] = (float)m;   // commitment_loss (identical forward value)
    }
}

extern "C" void kernel_launch(void* const* d_in, const int* in_sizes, int n_in,
                              void* d_out, int out_size, void* d_ws, size_t ws_size,
                              hipStream_t stream) {
    const float* x = (const float*)d_in[0];   // (64,1024,256)
    const float* v = (const float*)d_in[1];   // (256,4096)

    float* out      = (float*)d_out;
    float* out_q    = out;
    float* out_loss = out + (size_t)NROWS * DIM;
    float* out_idx  = out + (size_t)NROWS * DIM + 2;

    char*   ws      = (char*)d_ws;
    float*  cref    = (float*)ws;
    int4*   cand    = (int4*)(ws + 32768);
    float*  partial = (float*)(ws + 1081344);
    float*  vt      = (float*)(ws + 1343488);
    ushort* vth     = (ushort*)(ws + 5537792);

    vq_cref_kernel<<<KCB / 256, 256, 0, stream>>>(v, cref);
    vq_transpose_kernel<<<dim3(DIM / 32, KCB / 32), dim3(32, 8), 0, stream>>>(v, vt, vth);
    vq_mfma_argmin_kernel<<<NROWS / 64, 256, 0, stream>>>(x, vth, cref, cand);
    vq_emulate_kernel<<<NROWS * 4 / 256, 256, 0, stream>>>(x, vt, cref, cand, out_idx);
    vq_quant_kernel<<<NROWS / 4, 256, 0, stream>>>(x, vt, cand, out_q, partial);
    vq_finalize_kernel<<<1, 256, 0, stream>>>(partial, out_loss);
}